// Round 1
// 315.958 us; speedup vs baseline: 1.1364x; 1.1364x over previous
//
#include <hip/hip_runtime.h>

typedef unsigned short u16;
typedef unsigned int u32;
typedef __bf16 bf16x8 __attribute__((ext_vector_type(8)));
typedef __bf16 bf16x4 __attribute__((ext_vector_type(4)));
typedef short s16x4 __attribute__((ext_vector_type(4)));
typedef float f32x4 __attribute__((ext_vector_type(4)));

struct __align__(8) u16x4 { u16 x, y, z, w; };

__device__ __forceinline__ void async_copy16(const void* g, void* l) {
  __builtin_amdgcn_global_load_lds(
      (__attribute__((address_space(1))) void*)g,
      (__attribute__((address_space(3))) void*)l, 16, 0, 0);
}

__device__ __forceinline__ u16 f2bf(float f) {
  unsigned u = __builtin_bit_cast(unsigned, f);
  u = (u + 0x7FFFu + ((u >> 16) & 1u)) >> 16;
  return (u16)u;
}
__device__ __forceinline__ float bf2f(u16 h) {
  unsigned u = ((unsigned)h) << 16;
  return __builtin_bit_cast(float, u);
}

// NOTE: call amdgcn builtins DIRECTLY — host pass parses aux-target builtins,
// but __has_builtin() is false for them on host (round-3 compile failure).
__device__ __forceinline__ float fast_exp2(float x) {
  return __builtin_amdgcn_exp2f(x);
}
__device__ __forceinline__ float fast_rcp(float x) {
  return __builtin_amdgcn_rcpf(x);
}

__device__ __forceinline__ f32x4 mfma32(bf16x8 a, bf16x8 b, f32x4 c) {
  return __builtin_amdgcn_mfma_f32_16x16x32_bf16(a, b, c, 0, 0, 0);
}

// 16x16x16 bf16 MFMA (legacy shape, v4i16 operands; k = quad*4 + j)
__device__ __forceinline__ f32x4 mfma16(bf16x4 a, bf16x4 b, f32x4 c) {
  return __builtin_amdgcn_mfma_f32_16x16x16bf16_1k(
      __builtin_bit_cast(s16x4, a), __builtin_bit_cast(s16x4, b), c, 0, 0, 0);
}

// SCALE * log2(e), folded into Q at the gemm1 epilogue.
#define CEXP 0.18033688011112042f

// ---------------------------------------------------------------------------
// Mode detection (bf16 vs fp32 inputs) — see round-1 notes. flag=0 -> fp32.
// ---------------------------------------------------------------------------
__global__ void detect_mode(const u32* __restrict__ probe, int* __restrict__ flag) {
  __shared__ int cnt[256];
  int t = threadIdx.x;
  int c = 0;
#pragma unroll
  for (int j = 0; j < 16; ++j) {
    u32 v = probe[t + j * 256];
    unsigned e = (v >> 7) & 0xFFu;
    c += (e >= 100u && e <= 130u) ? 1 : 0;
  }
  cnt[t] = c;
  __syncthreads();
  for (int s = 128; s > 0; s >>= 1) {
    if (t < s) cnt[t] += cnt[t + s];
    __syncthreads();
  }
  if (t == 0) *flag = (cnt[0] * 2 > 4096) ? 1 : 0;
}

__global__ void convert_in(const void* __restrict__ src, u16* __restrict__ dst,
                           const int* __restrict__ flag, int n) {
  int mode = *flag;
  int i = (blockIdx.x * blockDim.x + threadIdx.x) * 8;
  if (i >= n) return;
  if (mode == 1) {
    *(uint4*)(dst + i) = *(const uint4*)((const u16*)src + i);
  } else {
    const float* s = (const float*)src;
    float4 a = *(const float4*)(s + i);
    float4 b = *(const float4*)(s + i + 4);
    uint4 o;
    o.x = (u32)f2bf(a.x) | ((u32)f2bf(a.y) << 16);
    o.y = (u32)f2bf(a.z) | ((u32)f2bf(a.w) << 16);
    o.z = (u32)f2bf(b.x) | ((u32)f2bf(b.y) << 16);
    o.w = (u32)f2bf(b.z) | ((u32)f2bf(b.w) << 16);
    *(uint4*)(dst + i) = o;
  }
}

// ---------------------------------------------------------------------------
// NT GEMM, 8-phase 256x256 schedule (m201 template, race-screened variant).
//   - 512 threads = 8 waves (2M x 4N); per-wave output 128x64 = 8x4 frags.
//   - BK=64, 2 K-tile LDS double-buffer: 2 x (A 32KB + B 32KB) = 128 KiB.
//   - T2: XOR swizzle (byte ^= (row&7)<<4). global_load_lds writes linearly,
//     so swizzle is applied to the GLOBAL source col + again on ds_read addr
//     (both-sides-or-neither, rule #21). Makes 128B-row-stride ds_read_b128
//     conflict-free (else 16-way).
//   - T3/T4: 4 phases per K-tile {ds_read quadrant, barrier, setprio(1),
//     16 MFMA, setprio(0), barrier}. Stage tile kb+2 into the just-consumed
//     buffer after its region's last-read barrier (A after phase 3, B after
//     phase 4). ONE s_waitcnt vmcnt(8) per K-tile: tile kb+1 guaranteed
//     landed, tile kb+2's 8 loads stay in flight (never drain to 0).
//   - T5: setprio around MFMA clusters (pays only under phase-split).
// Requires K >= 128 (nkb >= 2); both calls have K=1024.
// QKV mode (vT != nullptr): cols<1024 (Q) scaled by CEXP; cols>=2048 (V)
// stored transposed per head to vT.
// ---------------------------------------------------------------------------
__global__ __launch_bounds__(512, 2) void gemm_bt(
    const u16* __restrict__ A, const u16* __restrict__ Bm,
    u16* __restrict__ C, u16* __restrict__ vT, const u16* __restrict__ bias,
    float* __restrict__ outF, const int* __restrict__ flagp,
    int K, int ldc)
{
  // [buf][256 rows][64 k] bf16 per tensor; A at 0, B at 65536.
  __shared__ __align__(16) char lds[131072];

  const int t = threadIdx.x;
  const int lane = t & 63, wave = t >> 6;
  const int quad = lane >> 4, l16 = lane & 15;
  const int wn = wave & 3, wm = wave >> 2;
  const int rowbase = blockIdx.y * 256;
  const int colbase = blockIdx.x * 256;

  // ---- staging constants: thread t covers linear LDS bytes q*8192 + t*16.
  // row = q*64 + (t>>3); linear col byte = (t&7)*16; global source col is
  // pre-swizzled so that LDS[row][col] holds global[row][col ^ ((row&7)<<4)].
  const int srow = t >> 3;
  const int scol = ((t & 7) << 4) ^ ((srow & 7) << 4);
  const int wlds = wave << 10;   // wave-uniform LDS base within 8KB chunk

  const u16* Arow = A + (size_t)(rowbase + srow) * K + (scol >> 1);
  const u16* Brow = Bm + (size_t)(colbase + srow) * K + (scol >> 1);

  auto stageA = [&](int kb_, int buf_) {
#pragma unroll
    for (int q = 0; q < 4; ++q)
      async_copy16(Arow + (size_t)kb_ * 64 + (size_t)q * 64 * K,
                   lds + buf_ * 32768 + q * 8192 + wlds);
  };
  auto stageB = [&](int kb_, int buf_) {
#pragma unroll
    for (int q = 0; q < 4; ++q)
      async_copy16(Brow + (size_t)kb_ * 64 + (size_t)q * 64 * K,
                   lds + 65536 + buf_ * 32768 + q * 8192 + wlds);
  };

  f32x4 acc[8][4] = {};

  // ---- fragment-read bases. A row = wm*128 + ih*64 + i*16 + l16 (row stride
  // 128B); col byte = (ks*64 + quad*16) ^ ((row&7)<<4), row&7 == l16&7.
  const int swzl = (l16 & 7) << 4;
  const int c0 = (quad * 16) ^ swzl;
  const int c1 = (64 + quad * 16) ^ swzl;
  const char* Ard = lds + (size_t)(wm * 128 + l16) * 128;
  const char* Brd = lds + 65536 + (size_t)(wn * 64 + l16) * 128;

  // ---- prologue: tile0 -> buf0, tile1 -> buf1 (16 vmem ops). Wait oldest 8
  // (tile0), keep tile1 in flight.
  stageA(0, 0); stageB(0, 0);
  stageA(1, 1); stageB(1, 1);
  asm volatile("s_waitcnt vmcnt(8)" ::: "memory");
  __builtin_amdgcn_s_barrier();

  const int nkb = K >> 6;
  for (int kb = 0; kb < nkb; ++kb) {
    const int cur = kb & 1;
    const char* Ab = Ard + cur * 32768;
    const char* Bb = Brd + cur * 32768;
    bf16x8 aR[4][2], bR[2][2];

#define LOAD_A(ih_)                                                        \
  { _Pragma("unroll") for (int i = 0; i < 4; ++i) {                        \
      aR[i][0] = *(const bf16x8*)(Ab + (ih_) * 8192 + i * 2048 + c0);      \
      aR[i][1] = *(const bf16x8*)(Ab + (ih_) * 8192 + i * 2048 + c1); } }
#define LOAD_B(jh_)                                                        \
  { _Pragma("unroll") for (int j = 0; j < 2; ++j) {                        \
      bR[j][0] = *(const bf16x8*)(Bb + (jh_) * 4096 + j * 2048 + c0);      \
      bR[j][1] = *(const bf16x8*)(Bb + (jh_) * 4096 + j * 2048 + c1); } }
#define MFMA_Q(ih_, jh_)                                                   \
  { __builtin_amdgcn_s_barrier();                                          \
    __builtin_amdgcn_s_setprio(1);                                         \
    _Pragma("unroll") for (int i = 0; i < 4; ++i)                          \
    _Pragma("unroll") for (int j = 0; j < 2; ++j) {                        \
      acc[(ih_) * 4 + i][(jh_) * 2 + j] =                                  \
          mfma32(aR[i][0], bR[j][0], acc[(ih_) * 4 + i][(jh_) * 2 + j]);   \
      acc[(ih_) * 4 + i][(jh_) * 2 + j] =                                  \
          mfma32(aR[i][1], bR[j][1], acc[(ih_) * 4 + i][(jh_) * 2 + j]); } \
    __builtin_amdgcn_s_setprio(0);                                         \
    __builtin_amdgcn_s_barrier(); }

    // phase 1: quadrant (0,0)
    LOAD_A(0); LOAD_B(0); MFMA_Q(0, 0);
    // phase 2: quadrant (0,1) — A regs reused
    LOAD_B(1);            MFMA_Q(0, 1);
    // phase 3: quadrant (1,1) — B regs reused; after this barrier, ALL waves'
    // A-reads of buf[cur] have completed -> safe to overwrite A region.
    LOAD_A(1);            MFMA_Q(1, 1);
    if (kb + 2 < nkb) stageA(kb + 2, cur);
    // phase 4: quadrant (1,0) — re-read B jh0; after barrier, B region free.
    LOAD_B(0);            MFMA_Q(1, 0);
    if (kb + 2 < nkb) {
      stageB(kb + 2, cur);
      asm volatile("s_waitcnt vmcnt(8)" ::: "memory");  // tile kb+1 landed
      __builtin_amdgcn_s_barrier();
    } else if (kb + 1 < nkb) {
      asm volatile("s_waitcnt vmcnt(0)" ::: "memory");  // drain final tile
      __builtin_amdgcn_s_barrier();
    }
#undef LOAD_A
#undef LOAD_B
#undef MFMA_Q
  }

  // ---- epilogue. C/D frag layout: col = l16, row = quad*4 + r.
  if (vT != nullptr && colbase >= 2048) {
#pragma unroll
    for (int mi = 0; mi < 8; ++mi) {
      int rg = rowbase + wm * 128 + mi * 16 + quad * 4;
      int b = rg >> 11, n = rg & 2047;
#pragma unroll
      for (int nj = 0; nj < 4; ++nj) {
        int cg = colbase + wn * 64 + nj * 16 + l16;
        size_t idx = ((size_t)(b * 1024 + (cg - 2048))) * 2048 + n;
        u16x4 pk;
        pk.x = f2bf(acc[mi][nj][0]); pk.y = f2bf(acc[mi][nj][1]);
        pk.z = f2bf(acc[mi][nj][2]); pk.w = f2bf(acc[mi][nj][3]);
        *(u16x4*)(vT + idx) = pk;
      }
    }
  } else {
    const bool f32out = (flagp != nullptr) && (*flagp == 0);
    // Q-section scaling: fold SCALE*log2e into Q so attn's P = exp2(s) direct.
    const float scl = (vT != nullptr && colbase < 1024) ? CEXP : 1.0f;
#pragma unroll
    for (int nj = 0; nj < 4; ++nj) {
      int cg = colbase + wn * 64 + nj * 16 + l16;
      float bv = bias ? bf2f(bias[cg]) : 0.0f;
#pragma unroll
      for (int mi = 0; mi < 8; ++mi) {
#pragma unroll
        for (int r = 0; r < 4; ++r) {
          int rg = rowbase + wm * 128 + mi * 16 + quad * 4 + r;
          float val = acc[mi][nj][r] * scl + bv;
          if (f32out) outF[(size_t)rg * ldc + cg] = val;
          else        C[(size_t)rg * ldc + cg] = f2bf(val);
        }
      }
    }
  }
}

// ---------------------------------------------------------------------------
// Flash attention (unchanged from round 6): transpose-free P path, TK=64
// double-buffered, 4 blocks/CU, static softmax, Q pre-scaled by CEXP.
// ---------------------------------------------------------------------------
__global__ __launch_bounds__(256, 4) void attn_fwd(
    const u16* __restrict__ qk, const u16* __restrict__ vT, u16* __restrict__ outp)
{
  __shared__ __align__(16) u16 Ks[2][8][64][8];   // [buf][hd-chunk][key][8]
  __shared__ __align__(16) u16 Vs[2][8][64][8];   // [buf][key-chunk][e][8]

  const int t = threadIdx.x;
  const int lane = t & 63, wave = t >> 6;
  const int quad = lane >> 4, l16 = lane & 15;
  const int bh = blockIdx.x, b = bh >> 4, h = bh & 15;
  const int qtile = blockIdx.y;
  const size_t row0 = (size_t)b * 2048;

  bf16x8 qf[2][2];
  {
    const u16* qp = qk + (row0 + qtile * 128 + wave * 32 + l16) * 2048
                    + h * 64 + quad * 8;
#pragma unroll
    for (int i = 0; i < 2; ++i)
#pragma unroll
      for (int ks = 0; ks < 2; ++ks)
        qf[i][ks] = *(const bf16x8*)(qp + i * 16 * 2048 + ks * 32);
  }

  const u16* Kg[2]; const u16* Vg[2]; unsigned off2[2];
#pragma unroll
  for (int q = 0; q < 2; ++q) {
    int s = q * 256 + t;
    int row = s & 63, c = s >> 6;
    Kg[q] = qk + (row0 + row) * 2048 + (1024 + h * 64 + c * 8);
    Vg[q] = vT + (size_t)(b * 1024 + h * 64 + row) * 2048 + c * 8;
    off2[q] = (unsigned)(s & ~63) * 8;
  }

#pragma unroll
  for (int q = 0; q < 2; ++q) {
    async_copy16(Kg[q], (u16*)Ks + off2[q]);
    async_copy16(Vg[q], (u16*)Vs + off2[q]);
  }

  f32x4 o[2][4] = {};
  float l_r[2] = {0.0f, 0.0f};

  for (int kb = 0; kb < 32; ++kb) {
    const int cur = kb & 1, nxt = cur ^ 1;
    __syncthreads();
    if (kb < 31) {
#pragma unroll
      for (int q = 0; q < 2; ++q) {
        async_copy16(Kg[q] + (size_t)(kb + 1) * 64 * 2048,
                     (u16*)Ks + (unsigned)nxt * 4096 + off2[q]);
        async_copy16(Vg[q] + (kb + 1) * 64,
                     (u16*)Vs + (unsigned)nxt * 4096 + off2[q]);
      }
    }

    f32x4 sc[2][4] = {};
#pragma unroll
    for (int ks = 0; ks < 2; ++ks) {
#pragma unroll
      for (int j = 0; j < 4; ++j) {
        bf16x8 kf = *(const bf16x8*)&Ks[cur][ks * 4 + quad][j * 16 + l16][0];
#pragma unroll
        for (int i = 0; i < 2; ++i)
          sc[i][j] = __builtin_amdgcn_mfma_f32_16x16x32_bf16(kf, qf[i][ks], sc[i][j], 0, 0, 0);
      }
    }

#pragma unroll
    for (int jc = 0; jc < 4; ++jc) {
      bf16x4 vf[4];
#pragma unroll
      for (int et = 0; et < 4; ++et)
        vf[et] = *(const bf16x4*)&Vs[cur][jc * 2 + (quad >> 1)][et * 16 + l16][(quad & 1) * 4];
      bf16x4 pk[2];
#pragma unroll
      for (int i = 0; i < 2; ++i) {
        f32x4 pv;
#pragma unroll
        for (int r = 0; r < 4; ++r) {
          float p = fast_exp2(sc[i][jc][r]);
          pv[r] = p;
          l_r[i] += p;
        }
        pk[i] = __builtin_convertvector(pv, bf16x4);
      }
#pragma unroll
      for (int i = 0; i < 2; ++i)
#pragma unroll
        for (int et = 0; et < 4; ++et)
          o[i][et] = mfma16(pk[i], vf[et], o[i][et]);
    }
  }

#pragma unroll
  for (int i = 0; i < 2; ++i) {
    l_r[i] += __shfl_xor(l_r[i], 16, 64);
    l_r[i] += __shfl_xor(l_r[i], 32, 64);
    l_r[i] = fast_rcp(l_r[i]);
  }
#pragma unroll
  for (int i = 0; i < 2; ++i)
#pragma unroll
    for (int r = 0; r < 4; ++r) {
      float inv = __shfl(l_r[i], ((lane & 48) >> 2) + r, 64);
      int n = qtile * 128 + wave * 32 + i * 16 + quad * 4 + r;
      size_t base = (row0 + n) * 1024 + h * 64;
#pragma unroll
      for (int et = 0; et < 4; ++et)
        outp[base + et * 16 + l16] = f2bf(o[i][et][r] * inv);
    }
}

// ---------------------------------------------------------------------------
// Workspace (u16 elems): qkbuf 16777216 | vT 8388608 | xb/attn 8388608 |
// wqkvb 3145728 | flag. wprojb/bprojb alias vT after attn_fwd.
// ---------------------------------------------------------------------------
extern "C" void kernel_launch(void* const* d_in, const int* in_sizes, int n_in,
                              void* d_out, int out_size, void* d_ws, size_t ws_size,
                              hipStream_t stream) {
  (void)in_sizes; (void)n_in; (void)out_size; (void)ws_size;
  const void* x_in     = d_in[0];
  const void* wqkv_in  = d_in[1];
  const void* wproj_in = d_in[2];
  const void* bproj_in = d_in[3];

  u16* qkbuf  = (u16*)d_ws;
  u16* vT     = qkbuf + 16777216;
  u16* xb     = vT + 8388608;
  u16* wqkvb  = xb + 8388608;
  int* flag   = (int*)(wqkvb + 3145728);
  u16* attn   = xb;
  u16* wprojb = vT;
  u16* bprojb = vT + 1048576;

  detect_mode<<<1, 256, 0, stream>>>((const u32*)wqkv_in, flag);
  convert_in<<<4096, 256, 0, stream>>>(x_in, xb, flag, 8388608);
  convert_in<<<1536, 256, 0, stream>>>(wqkv_in, wqkvb, flag, 3145728);

  // 256x256 tiles: QKV = 12x32 blocks, proj = 4x32 blocks, 512 thr each.
  gemm_bt<<<dim3(12, 32), 512, 0, stream>>>(xb, wqkvb, qkbuf, vT, nullptr,
                                            nullptr, nullptr, 1024, 2048);
  attn_fwd<<<dim3(64, 16), 256, 0, stream>>>(qkbuf, vT, attn);

  convert_in<<<512, 256, 0, stream>>>(wproj_in, wprojb, flag, 1048576);
  convert_in<<<1, 256, 0, stream>>>(bproj_in, bprojb, flag, 1024);

  gemm_bt<<<dim3(4, 32), 512, 0, stream>>>(attn, wprojb, (u16*)d_out, nullptr,
                                           bprojb, (float*)d_out, flag, 1024, 1024);
}

// Round 2
// 294.394 us; speedup vs baseline: 1.2196x; 1.0732x over previous
//
#include <hip/hip_runtime.h>

typedef unsigned short u16;
typedef unsigned int u32;
typedef __bf16 bf16x8 __attribute__((ext_vector_type(8)));
typedef __bf16 bf16x4 __attribute__((ext_vector_type(4)));
typedef short s16x4 __attribute__((ext_vector_type(4)));
typedef float f32x4 __attribute__((ext_vector_type(4)));
typedef float f32x16 __attribute__((ext_vector_type(16)));
typedef unsigned int u32x2 __attribute__((ext_vector_type(2)));
typedef unsigned int u32x4 __attribute__((ext_vector_type(4)));

struct __align__(8) u16x4 { u16 x, y, z, w; };

__device__ __forceinline__ void async_copy16(const void* g, void* l) {
  __builtin_amdgcn_global_load_lds(
      (__attribute__((address_space(1))) void*)g,
      (__attribute__((address_space(3))) void*)l, 16, 0, 0);
}

__device__ __forceinline__ u16 f2bf(float f) {
  unsigned u = __builtin_bit_cast(unsigned, f);
  u = (u + 0x7FFFu + ((u >> 16) & 1u)) >> 16;
  return (u16)u;
}
__device__ __forceinline__ float bf2f(u16 h) {
  unsigned u = ((unsigned)h) << 16;
  return __builtin_bit_cast(float, u);
}

// NOTE: call amdgcn builtins DIRECTLY — host pass parses aux-target builtins,
// but __has_builtin() is false for them on host (round-3 compile failure).
__device__ __forceinline__ float fast_exp2(float x) {
  return __builtin_amdgcn_exp2f(x);
}
__device__ __forceinline__ float fast_rcp(float x) {
  return __builtin_amdgcn_rcpf(x);
}

__device__ __forceinline__ f32x4 mfma32(bf16x8 a, bf16x8 b, f32x4 c) {
  return __builtin_amdgcn_mfma_f32_16x16x32_bf16(a, b, c, 0, 0, 0);
}

// packed f32 pair -> 1 u32 of 2x bf16 (low = first arg). No builtin on gfx950.
__device__ __forceinline__ u32 cvt_pk_bf16(float lo, float hi) {
  u32 r;
  asm("v_cvt_pk_bf16_f32 %0, %1, %2" : "=v"(r) : "v"(lo), "v"(hi));
  return r;
}

// SCALE * log2(e), folded into Q at the gemm1 epilogue.
#define CEXP 0.18033688011112042f

// ---------------------------------------------------------------------------
// Mode detection (bf16 vs fp32 inputs) — see round-1 notes. flag=0 -> fp32.
// ---------------------------------------------------------------------------
__global__ void detect_mode(const u32* __restrict__ probe, int* __restrict__ flag) {
  __shared__ int cnt[256];
  int t = threadIdx.x;
  int c = 0;
#pragma unroll
  for (int j = 0; j < 16; ++j) {
    u32 v = probe[t + j * 256];
    unsigned e = (v >> 7) & 0xFFu;
    c += (e >= 100u && e <= 130u) ? 1 : 0;
  }
  cnt[t] = c;
  __syncthreads();
  for (int s = 128; s > 0; s >>= 1) {
    if (t < s) cnt[t] += cnt[t + s];
    __syncthreads();
  }
  if (t == 0) *flag = (cnt[0] * 2 > 4096) ? 1 : 0;
}

__global__ void convert_in(const void* __restrict__ src, u16* __restrict__ dst,
                           const int* __restrict__ flag, int n) {
  int mode = *flag;
  int i = (blockIdx.x * blockDim.x + threadIdx.x) * 8;
  if (i >= n) return;
  if (mode == 1) {
    *(uint4*)(dst + i) = *(const uint4*)((const u16*)src + i);
  } else {
    const float* s = (const float*)src;
    float4 a = *(const float4*)(s + i);
    float4 b = *(const float4*)(s + i + 4);
    uint4 o;
    o.x = (u32)f2bf(a.x) | ((u32)f2bf(a.y) << 16);
    o.y = (u32)f2bf(a.z) | ((u32)f2bf(a.w) << 16);
    o.z = (u32)f2bf(b.x) | ((u32)f2bf(b.y) << 16);
    o.w = (u32)f2bf(b.z) | ((u32)f2bf(b.w) << 16);
    *(uint4*)(dst + i) = o;
  }
}

// ---------------------------------------------------------------------------
// NT GEMM, 8-phase 256x256 schedule (m201 template) — unchanged from round 1
// (QKV gemm dropped out of the profile's top dispatches after this).
// ---------------------------------------------------------------------------
__global__ __launch_bounds__(512, 2) void gemm_bt(
    const u16* __restrict__ A, const u16* __restrict__ Bm,
    u16* __restrict__ C, u16* __restrict__ vT, const u16* __restrict__ bias,
    float* __restrict__ outF, const int* __restrict__ flagp,
    int K, int ldc)
{
  // [buf][256 rows][64 k] bf16 per tensor; A at 0, B at 65536.
  __shared__ __align__(16) char lds[131072];

  const int t = threadIdx.x;
  const int lane = t & 63, wave = t >> 6;
  const int quad = lane >> 4, l16 = lane & 15;
  const int wn = wave & 3, wm = wave >> 2;
  const int rowbase = blockIdx.y * 256;
  const int colbase = blockIdx.x * 256;

  const int srow = t >> 3;
  const int scol = ((t & 7) << 4) ^ ((srow & 7) << 4);
  const int wlds = wave << 10;

  const u16* Arow = A + (size_t)(rowbase + srow) * K + (scol >> 1);
  const u16* Brow = Bm + (size_t)(colbase + srow) * K + (scol >> 1);

  auto stageA = [&](int kb_, int buf_) {
#pragma unroll
    for (int q = 0; q < 4; ++q)
      async_copy16(Arow + (size_t)kb_ * 64 + (size_t)q * 64 * K,
                   lds + buf_ * 32768 + q * 8192 + wlds);
  };
  auto stageB = [&](int kb_, int buf_) {
#pragma unroll
    for (int q = 0; q < 4; ++q)
      async_copy16(Brow + (size_t)kb_ * 64 + (size_t)q * 64 * K,
                   lds + 65536 + buf_ * 32768 + q * 8192 + wlds);
  };

  f32x4 acc[8][4] = {};

  const int swzl = (l16 & 7) << 4;
  const int c0 = (quad * 16) ^ swzl;
  const int c1 = (64 + quad * 16) ^ swzl;
  const char* Ard = lds + (size_t)(wm * 128 + l16) * 128;
  const char* Brd = lds + 65536 + (size_t)(wn * 64 + l16) * 128;

  stageA(0, 0); stageB(0, 0);
  stageA(1, 1); stageB(1, 1);
  asm volatile("s_waitcnt vmcnt(8)" ::: "memory");
  __builtin_amdgcn_s_barrier();

  const int nkb = K >> 6;
  for (int kb = 0; kb < nkb; ++kb) {
    const int cur = kb & 1;
    const char* Ab = Ard + cur * 32768;
    const char* Bb = Brd + cur * 32768;
    bf16x8 aR[4][2], bR[2][2];

#define LOAD_A(ih_)                                                        \
  { _Pragma("unroll") for (int i = 0; i < 4; ++i) {                        \
      aR[i][0] = *(const bf16x8*)(Ab + (ih_) * 8192 + i * 2048 + c0);      \
      aR[i][1] = *(const bf16x8*)(Ab + (ih_) * 8192 + i * 2048 + c1); } }
#define LOAD_B(jh_)                                                        \
  { _Pragma("unroll") for (int j = 0; j < 2; ++j) {                        \
      bR[j][0] = *(const bf16x8*)(Bb + (jh_) * 4096 + j * 2048 + c0);      \
      bR[j][1] = *(const bf16x8*)(Bb + (jh_) * 4096 + j * 2048 + c1); } }
#define MFMA_Q(ih_, jh_)                                                   \
  { __builtin_amdgcn_s_barrier();                                          \
    __builtin_amdgcn_s_setprio(1);                                         \
    _Pragma("unroll") for (int i = 0; i < 4; ++i)                          \
    _Pragma("unroll") for (int j = 0; j < 2; ++j) {                        \
      acc[(ih_) * 4 + i][(jh_) * 2 + j] =                                  \
          mfma32(aR[i][0], bR[j][0], acc[(ih_) * 4 + i][(jh_) * 2 + j]);   \
      acc[(ih_) * 4 + i][(jh_) * 2 + j] =                                  \
          mfma32(aR[i][1], bR[j][1], acc[(ih_) * 4 + i][(jh_) * 2 + j]); } \
    __builtin_amdgcn_s_setprio(0);                                         \
    __builtin_amdgcn_s_barrier(); }

    LOAD_A(0); LOAD_B(0); MFMA_Q(0, 0);
    LOAD_B(1);            MFMA_Q(0, 1);
    LOAD_A(1);            MFMA_Q(1, 1);
    if (kb + 2 < nkb) stageA(kb + 2, cur);
    LOAD_B(0);            MFMA_Q(1, 0);
    if (kb + 2 < nkb) {
      stageB(kb + 2, cur);
      asm volatile("s_waitcnt vmcnt(8)" ::: "memory");
      __builtin_amdgcn_s_barrier();
    } else if (kb + 1 < nkb) {
      asm volatile("s_waitcnt vmcnt(0)" ::: "memory");
      __builtin_amdgcn_s_barrier();
    }
#undef LOAD_A
#undef LOAD_B
#undef MFMA_Q
  }

  if (vT != nullptr && colbase >= 2048) {
#pragma unroll
    for (int mi = 0; mi < 8; ++mi) {
      int rg = rowbase + wm * 128 + mi * 16 + quad * 4;
      int b = rg >> 11, n = rg & 2047;
#pragma unroll
      for (int nj = 0; nj < 4; ++nj) {
        int cg = colbase + wn * 64 + nj * 16 + l16;
        size_t idx = ((size_t)(b * 1024 + (cg - 2048))) * 2048 + n;
        u16x4 pk;
        pk.x = f2bf(acc[mi][nj][0]); pk.y = f2bf(acc[mi][nj][1]);
        pk.z = f2bf(acc[mi][nj][2]); pk.w = f2bf(acc[mi][nj][3]);
        *(u16x4*)(vT + idx) = pk;
      }
    }
  } else {
    const bool f32out = (flagp != nullptr) && (*flagp == 0);
    const float scl = (vT != nullptr && colbase < 1024) ? CEXP : 1.0f;
#pragma unroll
    for (int nj = 0; nj < 4; ++nj) {
      int cg = colbase + wn * 64 + nj * 16 + l16;
      float bv = bias ? bf2f(bias[cg]) : 0.0f;
#pragma unroll
      for (int mi = 0; mi < 8; ++mi) {
#pragma unroll
        for (int r = 0; r < 4; ++r) {
          int rg = rowbase + wm * 128 + mi * 16 + quad * 4 + r;
          float val = acc[mi][nj][r] * scl + bv;
          if (f32out) outF[(size_t)rg * ldc + cg] = val;
          else        C[(size_t)rg * ldc + cg] = f2bf(val);
        }
      }
    }
  }
}

// ---------------------------------------------------------------------------
// Flash attention — 32x32 MFMA rewrite (m214/§B structure).
//   - 4 waves x 32 queries; K-tile 64 keys, double-buffered.
//   - K_lds [64 keys][64 hd], V_lds [64 e][64 keys]: both row-major 128B rows
//     with XOR swizzle (byte ^= (row&7)<<4) staged via pre-swizzled global
//     source — the exact gemm_bt pattern that measures 0 bank conflicts.
//     All LDS reads are swizzled ds_read_b128.
//   - QK^T: mfma_f32_32x32x16_bf16(K, Q): D col = query = lane&31, rows =
//     keys (r&3)+8*(r>>2)+4*(lane>>5) — P row is lane-local; denominator
//     needs only one shfl_xor(,32) at the END (no per-tile reduce).
//   - PV: T12 repack: 16 cvt_pk_bf16 + 8 permlane32_swap per tile assemble
//     A-frags (verified map: swap(u0,u2).x->w0,.y->w2); PV = 8 mfma 32x32x16
//     per tile (vs 32 legacy mfma16 before) — MFMA issue per tile -38%.
//   - Static softmax preserved: Q pre-scaled by SCALE*log2e, P = exp2(s).
//   - setprio(1) around MFMA clusters (attn-proven +4-7%).
// LDS 32 KiB -> 4 blocks/CU. Grid (64 bh, 16 qtiles) x 256 thr unchanged.
// ---------------------------------------------------------------------------
__global__ __launch_bounds__(256, 4) void attn_fwd(
    const u16* __restrict__ qk, const u16* __restrict__ vT, u16* __restrict__ outp)
{
  __shared__ __align__(16) char sm[32768];  // K[2][8192] | V[2][8192]

  const int t = threadIdx.x;
  const int lane = t & 63, wave = t >> 6;
  const int l31 = lane & 31, h32 = lane >> 5;
  const int bh = blockIdx.x, b = bh >> 4, h = bh & 15;
  const int qtile = blockIdx.y;
  const size_t row0 = (size_t)b * 2048;
  const int qb = qtile * 128 + wave * 32;

  // Q fragments (B-operand of QK^T): qf[s] elem j = Q[query=l31][hd=s*16+h32*8+j]
  bf16x8 qf[4];
  {
    const u16* qp = qk + (row0 + qb + l31) * 2048 + h * 64 + h32 * 8;
#pragma unroll
    for (int s = 0; s < 4; ++s)
      qf[s] = *(const bf16x8*)(qp + s * 16);
  }

  // staging: thread-slot si covers LDS linear byte si*16; row = si>>3,
  // linear col = (si&7)*16; source col pre-swizzled by ((row&7)<<4).
  const u16* Kg[2]; const u16* Vg[2]; unsigned loff[2];
#pragma unroll
  for (int q = 0; q < 2; ++q) {
    int si = q * 256 + t;
    int srow = si >> 3;
    int scolb = ((si & 7) << 4) ^ ((srow & 7) << 4);
    Kg[q] = qk + (row0 + srow) * 2048 + 1024 + h * 64 + (scolb >> 1);
    Vg[q] = vT + ((size_t)(b * 1024 + h * 64 + srow)) * 2048 + (scolb >> 1);
    loff[q] = q * 4096 + wave * 1024;   // wave-uniform LDS base (+lane*16 by HW)
  }

#pragma unroll
  for (int q = 0; q < 2; ++q) {
    async_copy16(Kg[q], sm + loff[q]);
    async_copy16(Vg[q], sm + 16384 + loff[q]);
  }

  // swizzled read columns, shared by K reads (s-step) and V reads (k-block)
  const int swz = (lane & 7) << 4;
  int cswz[4];
#pragma unroll
  for (int s = 0; s < 4; ++s) cswz[s] = (s * 32 + h32 * 16) ^ swz;
  const int rowb = l31 * 128;

  f32x16 o2[2] = {};
  float lsum = 0.0f;

  for (int kb = 0; kb < 32; ++kb) {
    const int cur = kb & 1, nxt = cur ^ 1;
    __syncthreads();   // drains prefetch of buf[cur] (compiler vmcnt(0))
    if (kb < 31) {
#pragma unroll
      for (int q = 0; q < 2; ++q) {
        async_copy16(Kg[q] + (size_t)(kb + 1) * 64 * 2048, sm + nxt * 8192 + loff[q]);
        async_copy16(Vg[q] + (kb + 1) * 64, sm + 16384 + nxt * 8192 + loff[q]);
      }
    }
    const char* Kb = sm + cur * 8192;
    const char* Vb = sm + 16384 + cur * 8192;

#pragma unroll
    for (int kh = 0; kh < 2; ++kh) {
      // --- QK^T: 32 queries x 32 keys, HD=64 as 4 k16 steps
      f32x16 s2 = {};
      __builtin_amdgcn_s_setprio(1);
#pragma unroll
      for (int s = 0; s < 4; ++s) {
        bf16x8 kf = *(const bf16x8*)(Kb + kh * 4096 + rowb + cswz[s]);
        s2 = __builtin_amdgcn_mfma_f32_32x32x16_bf16(kf, qf[s], s2, 0, 0, 0);
      }
      __builtin_amdgcn_s_setprio(0);

      // --- static softmax: P = exp2(s), pack f32 pairs to bf16 u32s
      u32 u[8];
#pragma unroll
      for (int w = 0; w < 8; ++w) {
        float p0 = fast_exp2(s2[2 * w]);
        float p1 = fast_exp2(s2[2 * w + 1]);
        lsum += p0 + p1;
        u[w] = cvt_pk_bf16(p0, p1);
      }

      // --- T12 repack: A-frag keys h32*8+j. Lane key-map of u[w]:
      // u0={0,1} u1={2,3} u2={8,9} u3={10,11} u4={16,17} u5={18,19}
      // u6={24,25} u7={26,27} (all +4*h32). swap(u0,u2): .x = w0 (lower {0,1}/
      // upper {8,9}), .y = w2 (lower {4,5}/upper {12,13}).
      u32x2 r02 = __builtin_amdgcn_permlane32_swap(u[0], u[2], false, false);
      u32x2 r13 = __builtin_amdgcn_permlane32_swap(u[1], u[3], false, false);
      u32x2 r46 = __builtin_amdgcn_permlane32_swap(u[4], u[6], false, false);
      u32x2 r57 = __builtin_amdgcn_permlane32_swap(u[5], u[7], false, false);
      u32x4 fa0v; fa0v.x = r02.x; fa0v.y = r13.x; fa0v.z = r02.y; fa0v.w = r13.y;
      u32x4 fa1v; fa1v.x = r46.x; fa1v.y = r57.x; fa1v.z = r46.y; fa1v.w = r57.y;
      bf16x8 fa0 = __builtin_bit_cast(bf16x8, fa0v);   // keys kh*32 + 0..15
      bf16x8 fa1 = __builtin_bit_cast(bf16x8, fa1v);   // keys kh*32 + 16..31

      // --- PV: o2[eb] += P x V, V-frag = b128 [e-row][key] swizzled read
      __builtin_amdgcn_s_setprio(1);
#pragma unroll
      for (int eb = 0; eb < 2; ++eb) {
        bf16x8 v0 = *(const bf16x8*)(Vb + eb * 4096 + rowb + cswz[kh * 2 + 0]);
        o2[eb] = __builtin_amdgcn_mfma_f32_32x32x16_bf16(fa0, v0, o2[eb], 0, 0, 0);
        bf16x8 v1 = *(const bf16x8*)(Vb + eb * 4096 + rowb + cswz[kh * 2 + 1]);
        o2[eb] = __builtin_amdgcn_mfma_f32_32x32x16_bf16(fa1, v1, o2[eb], 0, 0, 0);
      }
      __builtin_amdgcn_s_setprio(0);
    }
  }

  // denominator: full row sum lives split across lane l and l^32
  lsum += __shfl_xor(lsum, 32, 64);
  float inv = fast_rcp(lsum);

  // O layout: col(lane&31) = e, rows = queries (r&3)+8*(r>>2)+4*h32
#pragma unroll
  for (int r = 0; r < 16; ++r) {
    int qr = (r & 3) + 8 * (r >> 2) + 4 * h32;
    float iv = __shfl(inv, qr, 64);
    size_t base = (row0 + qb + qr) * 1024 + h * 64 + l31;
    outp[base]      = f2bf(o2[0][r] * iv);
    outp[base + 32] = f2bf(o2[1][r] * iv);
  }
}

// ---------------------------------------------------------------------------
// Workspace (u16 elems): qkbuf 16777216 | vT 8388608 | xb/attn 8388608 |
// wqkvb 3145728 | flag. wprojb/bprojb alias vT after attn_fwd.
// ---------------------------------------------------------------------------
extern "C" void kernel_launch(void* const* d_in, const int* in_sizes, int n_in,
                              void* d_out, int out_size, void* d_ws, size_t ws_size,
                              hipStream_t stream) {
  (void)in_sizes; (void)n_in; (void)out_size; (void)ws_size;
  const void* x_in     = d_in[0];
  const void* wqkv_in  = d_in[1];
  const void* wproj_in = d_in[2];
  const void* bproj_in = d_in[3];

  u16* qkbuf  = (u16*)d_ws;
  u16* vT     = qkbuf + 16777216;
  u16* xb     = vT + 8388608;
  u16* wqkvb  = xb + 8388608;
  int* flag   = (int*)(wqkvb + 3145728);
  u16* attn   = xb;
  u16* wprojb = vT;
  u16* bprojb = vT + 1048576;

  detect_mode<<<1, 256, 0, stream>>>((const u32*)wqkv_in, flag);
  convert_in<<<4096, 256, 0, stream>>>(x_in, xb, flag, 8388608);
  convert_in<<<1536, 256, 0, stream>>>(wqkv_in, wqkvb, flag, 3145728);

  gemm_bt<<<dim3(12, 32), 512, 0, stream>>>(xb, wqkvb, qkbuf, vT, nullptr,
                                            nullptr, nullptr, 1024, 2048);
  attn_fwd<<<dim3(64, 16), 256, 0, stream>>>(qkbuf, vT, attn);

  convert_in<<<512, 256, 0, stream>>>(wproj_in, wprojb, flag, 1048576);
  convert_in<<<1, 256, 0, stream>>>(bproj_in, bprojb, flag, 1024);

  gemm_bt<<<dim3(4, 32), 512, 0, stream>>>(attn, wprojb, (u16*)d_out, nullptr,
                                           bprojb, (float*)d_out, flag, 1024, 1024);
}

// Round 3
// 267.513 us; speedup vs baseline: 1.3422x; 1.1005x over previous
//
#include <hip/hip_runtime.h>

typedef unsigned short u16;
typedef unsigned int u32;
typedef __bf16 bf16x8 __attribute__((ext_vector_type(8)));
typedef __bf16 bf16x4 __attribute__((ext_vector_type(4)));
typedef short s16x4 __attribute__((ext_vector_type(4)));
typedef float f32x4 __attribute__((ext_vector_type(4)));
typedef float f32x16 __attribute__((ext_vector_type(16)));
typedef unsigned int u32x2 __attribute__((ext_vector_type(2)));
typedef unsigned int u32x4 __attribute__((ext_vector_type(4)));

struct __align__(8) u16x4 { u16 x, y, z, w; };

__device__ __forceinline__ void async_copy16(const void* g, void* l) {
  __builtin_amdgcn_global_load_lds(
      (__attribute__((address_space(1))) void*)g,
      (__attribute__((address_space(3))) void*)l, 16, 0, 0);
}

__device__ __forceinline__ u16 f2bf(float f) {
  unsigned u = __builtin_bit_cast(unsigned, f);
  u = (u + 0x7FFFu + ((u >> 16) & 1u)) >> 16;
  return (u16)u;
}
__device__ __forceinline__ float bf2f(u16 h) {
  unsigned u = ((unsigned)h) << 16;
  return __builtin_bit_cast(float, u);
}

// NOTE: call amdgcn builtins DIRECTLY — host pass parses aux-target builtins,
// but __has_builtin() is false for them on host (round-3 compile failure).
__device__ __forceinline__ float fast_exp2(float x) {
  return __builtin_amdgcn_exp2f(x);
}
__device__ __forceinline__ float fast_rcp(float x) {
  return __builtin_amdgcn_rcpf(x);
}

__device__ __forceinline__ f32x4 mfma32(bf16x8 a, bf16x8 b, f32x4 c) {
  return __builtin_amdgcn_mfma_f32_16x16x32_bf16(a, b, c, 0, 0, 0);
}

// packed f32 pair -> 1 u32 of 2x bf16 (low = first arg). No builtin on gfx950.
__device__ __forceinline__ u32 cvt_pk_bf16(float lo, float hi) {
  u32 r;
  asm("v_cvt_pk_bf16_f32 %0, %1, %2" : "=v"(r) : "v"(lo), "v"(hi));
  return r;
}

// SCALE * log2(e), folded into Q at the gemm1 epilogue.
#define CEXP 0.18033688011112042f

// ---------------------------------------------------------------------------
// Mode detection (bf16 vs fp32 inputs) — see round-1 notes. flag=0 -> fp32.
// ---------------------------------------------------------------------------
__global__ void detect_mode(const u32* __restrict__ probe, int* __restrict__ flag) {
  __shared__ int cnt[256];
  int t = threadIdx.x;
  int c = 0;
#pragma unroll
  for (int j = 0; j < 16; ++j) {
    u32 v = probe[t + j * 256];
    unsigned e = (v >> 7) & 0xFFu;
    c += (e >= 100u && e <= 130u) ? 1 : 0;
  }
  cnt[t] = c;
  __syncthreads();
  for (int s = 128; s > 0; s >>= 1) {
    if (t < s) cnt[t] += cnt[t + s];
    __syncthreads();
  }
  if (t == 0) *flag = (cnt[0] * 2 > 4096) ? 1 : 0;
}

__global__ void convert_in(const void* __restrict__ src, u16* __restrict__ dst,
                           const int* __restrict__ flag, int n) {
  int mode = *flag;
  int i = (blockIdx.x * blockDim.x + threadIdx.x) * 8;
  if (i >= n) return;
  if (mode == 1) {
    *(uint4*)(dst + i) = *(const uint4*)((const u16*)src + i);
  } else {
    const float* s = (const float*)src;
    float4 a = *(const float4*)(s + i);
    float4 b = *(const float4*)(s + i + 4);
    uint4 o;
    o.x = (u32)f2bf(a.x) | ((u32)f2bf(a.y) << 16);
    o.y = (u32)f2bf(a.z) | ((u32)f2bf(a.w) << 16);
    o.z = (u32)f2bf(b.x) | ((u32)f2bf(b.y) << 16);
    o.w = (u32)f2bf(b.z) | ((u32)f2bf(b.w) << 16);
    *(uint4*)(dst + i) = o;
  }
}

// ---------------------------------------------------------------------------
// NT GEMM, 256 x (NJ*64) tile, BK=64, 2-phase K-loop.
// Round-2 theory: the 4-phase/9-barrier loop serialized LDS+MFMA per phase
// (2.65 us/K-tile vs 0.86 MFMA floor) and grids packed badly (384 blk = 2
// uneven rounds; proj 128 blk = half GPU). Changes:
//   - template<NJ>: BN = NJ*64. QKV NJ=3 -> grid 16x32 = 512 = 2 EXACT
//     rounds (LDS 112KB); proj NJ=2 -> grid 8x32 = 256 = 1 round (96KB).
//   - 2 phases/K-tile, 5 barriers (was 9): ph1 {A-half0 + all B reads |
//     bar | 4*NJ*2 MFMA | bar} stageB(kb+2); ph2 {A-half1 | bar | MFMA |
//     bar} stageA(kb+2); vmcnt(NJ+4) counted (tile kb+1 landed, kb+2 in
//     flight); bar. Region safety: B last read ph1, A last read ph2, each
//     staged only after its closing barrier (all-waves lgkm drained).
//   - bijective XCD swizzle (nwg%8==0): same-rowbase blocks share one XCD's
//     L2 -> A-panels fetched ~1x per XCD instead of ~8x (FETCH 84->~50MB).
//   - T2 XOR swizzle unchanged (byte ^= (row&7)<<4, both-sides).
// Epilogue is per-column: BN=192 tiles straddle Q|K|V boundaries (1024/2048).
// ---------------------------------------------------------------------------
template<int NJ>
__global__ __launch_bounds__(512, 2) void gemm_bt(
    const u16* __restrict__ A, const u16* __restrict__ Bm,
    u16* __restrict__ C, u16* __restrict__ vT, const u16* __restrict__ bias,
    float* __restrict__ outF, const int* __restrict__ flagp,
    int K, int ldc)
{
  // A dbuf [2][256][64] @0 (64KB); B dbuf [2][NJ*64][64] @65536.
  __shared__ __align__(16) char lds[65536 + NJ * 16384];

  const int t = threadIdx.x;
  const int lane = t & 63, wave = t >> 6;
  const int quad = lane >> 4, l16 = lane & 15;
  const int wn = wave & 3, wm = wave >> 2;

  // XCD-chunked bijective remap: blocks with equal rowbase share an XCD.
  const int nwg = gridDim.x * gridDim.y;
  int bid = blockIdx.y * gridDim.x + blockIdx.x;
  bid = (bid & 7) * (nwg >> 3) + (bid >> 3);
  const int rowbase = (bid / gridDim.x) * 256;
  const int colbase = (bid % gridDim.x) * (NJ * 64);

  // staging: thread t covers LDS linear bytes q*8192 + t*16 of each region.
  const int srow = t >> 3;
  const int scol = ((t & 7) << 4) ^ ((srow & 7) << 4);
  const int wlds = wave << 10;

  const u16* Arow = A + (size_t)(rowbase + srow) * K + (scol >> 1);
  const u16* Brow = Bm + (size_t)(colbase + srow) * K + (scol >> 1);

  auto stageA = [&](int kb_, int buf_) {
#pragma unroll
    for (int q = 0; q < 4; ++q)
      async_copy16(Arow + (size_t)kb_ * 64 + (size_t)q * 64 * K,
                   lds + buf_ * 32768 + q * 8192 + wlds);
  };
  auto stageB = [&](int kb_, int buf_) {
#pragma unroll
    for (int q = 0; q < NJ; ++q)
      async_copy16(Brow + (size_t)kb_ * 64 + (size_t)q * 64 * K,
                   lds + 65536 + buf_ * (NJ * 8192) + q * 8192 + wlds);
  };

  f32x4 acc[8][NJ] = {};

  // fragment-read bases; row byte-swizzle uses row&7 == l16&7.
  const int swzl = (l16 & 7) << 4;
  const int c0 = (quad * 16) ^ swzl;
  const int c1 = (64 + quad * 16) ^ swzl;
  const char* Ard = lds + (size_t)(wm * 128 + l16) * 128;
  const char* Brd = lds + 65536 + (size_t)(wn * (NJ * 16) + l16) * 128;

  // prologue: tile0 -> buf0, tile1 -> buf1; drain tile0, keep tile1 in flight.
  stageA(0, 0); stageB(0, 0);
  stageA(1, 1); stageB(1, 1);
  if constexpr (NJ == 3) asm volatile("s_waitcnt vmcnt(7)" ::: "memory");
  else                   asm volatile("s_waitcnt vmcnt(6)" ::: "memory");
  __builtin_amdgcn_s_barrier();

  const int nkb = K >> 6;
  for (int kb = 0; kb < nkb; ++kb) {
    const int cur = kb & 1;
    const char* Ab = Ard + cur * 32768;
    const char* Bb = Brd + cur * (NJ * 8192);
    bf16x8 aR[4][2], bR[NJ][2];

    // ---- phase 1: A-half 0 + all B
#pragma unroll
    for (int i = 0; i < 4; ++i) {
      aR[i][0] = *(const bf16x8*)(Ab + i * 2048 + c0);
      aR[i][1] = *(const bf16x8*)(Ab + i * 2048 + c1);
    }
#pragma unroll
    for (int j = 0; j < NJ; ++j) {
      bR[j][0] = *(const bf16x8*)(Bb + j * 2048 + c0);
      bR[j][1] = *(const bf16x8*)(Bb + j * 2048 + c1);
    }
    __builtin_amdgcn_s_barrier();
    __builtin_amdgcn_s_setprio(1);
#pragma unroll
    for (int i = 0; i < 4; ++i)
#pragma unroll
      for (int j = 0; j < NJ; ++j) {
        acc[i][j] = mfma32(aR[i][0], bR[j][0], acc[i][j]);
        acc[i][j] = mfma32(aR[i][1], bR[j][1], acc[i][j]);
      }
    __builtin_amdgcn_s_setprio(0);
    __builtin_amdgcn_s_barrier();
    if (kb + 2 < nkb) stageB(kb + 2, cur);   // B region fully consumed

    // ---- phase 2: A-half 1 (reuse bR)
#pragma unroll
    for (int i = 0; i < 4; ++i) {
      aR[i][0] = *(const bf16x8*)(Ab + 8192 + i * 2048 + c0);
      aR[i][1] = *(const bf16x8*)(Ab + 8192 + i * 2048 + c1);
    }
    __builtin_amdgcn_s_barrier();
    __builtin_amdgcn_s_setprio(1);
#pragma unroll
    for (int i = 0; i < 4; ++i)
#pragma unroll
      for (int j = 0; j < NJ; ++j) {
        acc[4 + i][j] = mfma32(aR[i][0], bR[j][0], acc[4 + i][j]);
        acc[4 + i][j] = mfma32(aR[i][1], bR[j][1], acc[4 + i][j]);
      }
    __builtin_amdgcn_s_setprio(0);
    __builtin_amdgcn_s_barrier();

    if (kb + 2 < nkb) {
      stageA(kb + 2, cur);                    // A region fully consumed
      if constexpr (NJ == 3) asm volatile("s_waitcnt vmcnt(7)" ::: "memory");
      else                   asm volatile("s_waitcnt vmcnt(6)" ::: "memory");
      __builtin_amdgcn_s_barrier();
    } else if (kb + 1 < nkb) {
      asm volatile("s_waitcnt vmcnt(0)" ::: "memory");
      __builtin_amdgcn_s_barrier();
    }
  }

  // ---- epilogue, per-column (tiles straddle Q|K|V boundaries).
  const bool f32out = (flagp != nullptr) && (*flagp == 0);
#pragma unroll
  for (int nj = 0; nj < NJ; ++nj) {
    int cg = colbase + wn * (NJ * 16) + nj * 16 + l16;
    if (vT != nullptr && cg >= 2048) {
      // V section -> per-head transposed store
#pragma unroll
      for (int mi = 0; mi < 8; ++mi) {
        int rg = rowbase + wm * 128 + mi * 16 + quad * 4;
        int b = rg >> 11, n = rg & 2047;
        size_t idx = ((size_t)(b * 1024 + (cg - 2048))) * 2048 + n;
        u16x4 pk;
        pk.x = f2bf(acc[mi][nj][0]); pk.y = f2bf(acc[mi][nj][1]);
        pk.z = f2bf(acc[mi][nj][2]); pk.w = f2bf(acc[mi][nj][3]);
        *(u16x4*)(vT + idx) = pk;
      }
    } else {
      const float scl = (vT != nullptr && cg < 1024) ? CEXP : 1.0f;
      float bv = bias ? bf2f(bias[cg]) : 0.0f;
#pragma unroll
      for (int mi = 0; mi < 8; ++mi) {
#pragma unroll
        for (int r = 0; r < 4; ++r) {
          int rg = rowbase + wm * 128 + mi * 16 + quad * 4 + r;
          float val = acc[mi][nj][r] * scl + bv;
          if (f32out) outF[(size_t)rg * ldc + cg] = val;
          else        C[(size_t)rg * ldc + cg] = f2bf(val);
        }
      }
    }
  }
}

// ---------------------------------------------------------------------------
// Flash attention — 32x32 MFMA structure (round-2), unchanged this round.
// ---------------------------------------------------------------------------
__global__ __launch_bounds__(256, 4) void attn_fwd(
    const u16* __restrict__ qk, const u16* __restrict__ vT, u16* __restrict__ outp)
{
  __shared__ __align__(16) char sm[32768];  // K[2][8192] | V[2][8192]

  const int t = threadIdx.x;
  const int lane = t & 63, wave = t >> 6;
  const int l31 = lane & 31, h32 = lane >> 5;
  const int bh = blockIdx.x, b = bh >> 4, h = bh & 15;
  const int qtile = blockIdx.y;
  const size_t row0 = (size_t)b * 2048;
  const int qb = qtile * 128 + wave * 32;

  bf16x8 qf[4];
  {
    const u16* qp = qk + (row0 + qb + l31) * 2048 + h * 64 + h32 * 8;
#pragma unroll
    for (int s = 0; s < 4; ++s)
      qf[s] = *(const bf16x8*)(qp + s * 16);
  }

  const u16* Kg[2]; const u16* Vg[2]; unsigned loff[2];
#pragma unroll
  for (int q = 0; q < 2; ++q) {
    int si = q * 256 + t;
    int srow = si >> 3;
    int scolb = ((si & 7) << 4) ^ ((srow & 7) << 4);
    Kg[q] = qk + (row0 + srow) * 2048 + 1024 + h * 64 + (scolb >> 1);
    Vg[q] = vT + ((size_t)(b * 1024 + h * 64 + srow)) * 2048 + (scolb >> 1);
    loff[q] = q * 4096 + wave * 1024;
  }

#pragma unroll
  for (int q = 0; q < 2; ++q) {
    async_copy16(Kg[q], sm + loff[q]);
    async_copy16(Vg[q], sm + 16384 + loff[q]);
  }

  const int swz = (lane & 7) << 4;
  int cswz[4];
#pragma unroll
  for (int s = 0; s < 4; ++s) cswz[s] = (s * 32 + h32 * 16) ^ swz;
  const int rowb = l31 * 128;

  f32x16 o2[2] = {};
  float lsum = 0.0f;

  for (int kb = 0; kb < 32; ++kb) {
    const int cur = kb & 1, nxt = cur ^ 1;
    __syncthreads();
    if (kb < 31) {
#pragma unroll
      for (int q = 0; q < 2; ++q) {
        async_copy16(Kg[q] + (size_t)(kb + 1) * 64 * 2048, sm + nxt * 8192 + loff[q]);
        async_copy16(Vg[q] + (kb + 1) * 64, sm + 16384 + nxt * 8192 + loff[q]);
      }
    }
    const char* Kb = sm + cur * 8192;
    const char* Vb = sm + 16384 + cur * 8192;

#pragma unroll
    for (int kh = 0; kh < 2; ++kh) {
      f32x16 s2 = {};
      __builtin_amdgcn_s_setprio(1);
#pragma unroll
      for (int s = 0; s < 4; ++s) {
        bf16x8 kf = *(const bf16x8*)(Kb + kh * 4096 + rowb + cswz[s]);
        s2 = __builtin_amdgcn_mfma_f32_32x32x16_bf16(kf, qf[s], s2, 0, 0, 0);
      }
      __builtin_amdgcn_s_setprio(0);

      u32 u[8];
#pragma unroll
      for (int w = 0; w < 8; ++w) {
        float p0 = fast_exp2(s2[2 * w]);
        float p1 = fast_exp2(s2[2 * w + 1]);
        lsum += p0 + p1;
        u[w] = cvt_pk_bf16(p0, p1);
      }

      u32x2 r02 = __builtin_amdgcn_permlane32_swap(u[0], u[2], false, false);
      u32x2 r13 = __builtin_amdgcn_permlane32_swap(u[1], u[3], false, false);
      u32x2 r46 = __builtin_amdgcn_permlane32_swap(u[4], u[6], false, false);
      u32x2 r57 = __builtin_amdgcn_permlane32_swap(u[5], u[7], false, false);
      u32x4 fa0v; fa0v.x = r02.x; fa0v.y = r13.x; fa0v.z = r02.y; fa0v.w = r13.y;
      u32x4 fa1v; fa1v.x = r46.x; fa1v.y = r57.x; fa1v.z = r46.y; fa1v.w = r57.y;
      bf16x8 fa0 = __builtin_bit_cast(bf16x8, fa0v);
      bf16x8 fa1 = __builtin_bit_cast(bf16x8, fa1v);

      __builtin_amdgcn_s_setprio(1);
#pragma unroll
      for (int eb = 0; eb < 2; ++eb) {
        bf16x8 v0 = *(const bf16x8*)(Vb + eb * 4096 + rowb + cswz[kh * 2 + 0]);
        o2[eb] = __builtin_amdgcn_mfma_f32_32x32x16_bf16(fa0, v0, o2[eb], 0, 0, 0);
        bf16x8 v1 = *(const bf16x8*)(Vb + eb * 4096 + rowb + cswz[kh * 2 + 1]);
        o2[eb] = __builtin_amdgcn_mfma_f32_32x32x16_bf16(fa1, v1, o2[eb], 0, 0, 0);
      }
      __builtin_amdgcn_s_setprio(0);
    }
  }

  lsum += __shfl_xor(lsum, 32, 64);
  float inv = fast_rcp(lsum);

#pragma unroll
  for (int r = 0; r < 16; ++r) {
    int qr = (r & 3) + 8 * (r >> 2) + 4 * h32;
    float iv = __shfl(inv, qr, 64);
    size_t base = (row0 + qb + qr) * 1024 + h * 64 + l31;
    outp[base]      = f2bf(o2[0][r] * iv);
    outp[base + 32] = f2bf(o2[1][r] * iv);
  }
}

// ---------------------------------------------------------------------------
// Workspace (u16 elems): qkbuf 16777216 | vT 8388608 | xb/attn 8388608 |
// wqkvb 3145728 | flag. wprojb/bprojb alias vT after attn_fwd.
// ---------------------------------------------------------------------------
extern "C" void kernel_launch(void* const* d_in, const int* in_sizes, int n_in,
                              void* d_out, int out_size, void* d_ws, size_t ws_size,
                              hipStream_t stream) {
  (void)in_sizes; (void)n_in; (void)out_size; (void)ws_size;
  const void* x_in     = d_in[0];
  const void* wqkv_in  = d_in[1];
  const void* wproj_in = d_in[2];
  const void* bproj_in = d_in[3];

  u16* qkbuf  = (u16*)d_ws;
  u16* vT     = qkbuf + 16777216;
  u16* xb     = vT + 8388608;
  u16* wqkvb  = xb + 8388608;
  int* flag   = (int*)(wqkvb + 3145728);
  u16* attn   = xb;
  u16* wprojb = vT;
  u16* bprojb = vT + 1048576;

  detect_mode<<<1, 256, 0, stream>>>((const u32*)wqkv_in, flag);
  convert_in<<<4096, 256, 0, stream>>>(x_in, xb, flag, 8388608);
  convert_in<<<1536, 256, 0, stream>>>(wqkv_in, wqkvb, flag, 3145728);

  // QKV: 256x192 tiles -> 16x32 = 512 blocks = 2 exact rounds.
  gemm_bt<3><<<dim3(16, 32), 512, 0, stream>>>(xb, wqkvb, qkbuf, vT, nullptr,
                                               nullptr, nullptr, 1024, 2048);
  attn_fwd<<<dim3(64, 16), 256, 0, stream>>>(qkbuf, vT, attn);

  convert_in<<<512, 256, 0, stream>>>(wproj_in, wprojb, flag, 1048576);
  convert_in<<<1, 256, 0, stream>>>(bproj_in, bprojb, flag, 1024);

  // proj: 256x128 tiles -> 8x32 = 256 blocks = 1 exact round.
  gemm_bt<2><<<dim3(8, 32), 512, 0, stream>>>(attn, wprojb, (u16*)d_out, nullptr,
                                              bprojb, (float*)d_out, flag, 1024, 1024);
}